// Round 6
// baseline (318.014 us; speedup 1.0000x reference)
//
#include <hip/hip_runtime.h>

// SJLT projection: out[b, idx[d,j]] += x[b,d] * sign(d,j), * 1/sqrt(4)
// B=64, D=524288, P=8192, C=4.
//
// Model so far (R1-R11):
//  - LDS fp atomics (ds_add_f32): ~3.2 cyc/LANE serialized -> never for data.
//  - Random 4B global stores: 64B HBM write-back EACH. L2 no-write-allocate;
//    pretouch does NOT help (R9); spatial partitioning does NOT help (R8).
//    => only LDS-staged coalesced chunk writes avoid the 10x inflation.
//  - Harness re-poisons the full 512 MB ws INSIDE the timed region:
//    __amd_rocclr_fillBufferAligned = 82 us every iteration (R11 counters).
//    Uncontrollable floor ~= 82 + launch overhead + our kernels.
//  - R11 = 305.5: gather6 81 us with 19.1M LDS bank conflicts -- csr stride
//    CAP=384 = 0 mod 32 makes bank = sl%32 (pl-independent). transpose+binA
//    ~100 us serial, never in top-5 individually.
// R12: (a) fuse transpose+binA into ONE dispatch (independent work, LDS
// unioned, binA atomics hide under transpose streaming); (b) gather7 = cs r
// stride 385 (bank = (pl+sl)%32) to kill the 19.1M conflicts.

constexpr int BATCH = 64;
constexpr int DIM   = 524288;
constexpr int PROJ  = 8192;
constexpr int NENT  = DIM * 4;          // 2,097,152 entries
constexpr int CAP   = 384;              // per-p entry cap (proven R7-R11)
constexpr int CSTR  = 385;              // csr LDS row stride (=1 mod 32)

constexpr int NBLKA = 256;              // binA blocks
constexpr int EPB   = NENT / NBLKA;     // 8192 entries per binA block
constexpr int NBUCK = 256;              // coarse buckets
constexpr int BUCKP = PROJ / NBUCK;     // 32 p per bucket
constexpr int CAPB  = 80;               // per (bucket, blockA) cap: mean 32
constexpr int TBLK  = 2048;             // transpose blocks (256 d each)

// ------------------------------------------------ helpers
__device__ __forceinline__ uint32_t f2bf(float f) {   // RNE f32 -> bf16 bits
    uint32_t u = __float_as_uint(f);
    return (u + 0x7fffu + ((u >> 16) & 1u)) >> 16;
}

// ==================== pass 1: fused binA + transpose ====================
// Blocks [0,256): binA -- count/scan/compact 8192 entries into 256 coarse
// buckets (32 p each), coalesced chunk writes to coarse[(b*NBLKA+blk)*CAPB].
// Blocks [256,2304): transpose -- 256 d's each, x tile -> bf16-pair xT rows
// (scale 0.5 folded). LDS unioned (36 KB) -> 2+ blocks/CU; binA's LDS-atomic
// serialization hides under co-resident transpose streaming.
__global__ __launch_bounds__(1024) void prep_kernel(
    const float* __restrict__ x, const int4* __restrict__ idx4,
    const int4* __restrict__ sgn4, uint32_t* __restrict__ cntAB,
    uint32_t* __restrict__ coarse, uint32_t* __restrict__ xT)
{
    __shared__ uint32_t sh[8964];        // 35,856 B, unioned
    const int t = threadIdx.x;

    if (blockIdx.x < NBLKA) {
        // ---------------- binA ----------------
        uint32_t* cntL    = sh;          // 256
        uint32_t* offL    = sh + 256;    // 256
        uint32_t* curL    = sh + 512;    // 256
        uint32_t* wsumA   = sh + 768;    // 4
        uint32_t* staging = sh + 772;    // 8192 (32 KB)
        const int lane = t & 63;
        const int blk  = blockIdx.x;

        if (t < NBUCK) cntL[t] = 0;
        __syncthreads();

        int4 iv[2], sv[2];
        int  dd[2];
#pragma unroll
        for (int j = 0; j < 2; ++j) {
            int d = blk * 2048 + j * 1024 + t;
            dd[j] = d;
            iv[j] = idx4[d];
            sv[j] = sgn4[d];
        }
#pragma unroll
        for (int j = 0; j < 2; ++j) {
            atomicAdd(&cntL[(uint32_t)iv[j].x >> 5], 1u);
            atomicAdd(&cntL[(uint32_t)iv[j].y >> 5], 1u);
            atomicAdd(&cntL[(uint32_t)iv[j].z >> 5], 1u);
            atomicAdd(&cntL[(uint32_t)iv[j].w >> 5], 1u);
        }
        __syncthreads();
        // exclusive scan of cntL[256] (first 4 waves)
        uint32_t v = 0, s = 0;
        if (t < NBUCK) {
            s = cntL[t]; v = s;
#pragma unroll
            for (int off = 1; off < 64; off <<= 1) {
                uint32_t u = __shfl_up(v, off);
                if (lane >= off) v += u;
            }
            if (lane == 63) wsumA[t >> 6] = v;
        }
        __syncthreads();
        if (t < NBUCK) {
            uint32_t wb = 0;
            for (int w0 = 0; w0 < (t >> 6); ++w0) wb += wsumA[w0];
            uint32_t ex = wb + v - s;
            offL[t] = ex;
            curL[t] = ex;
        }
        __syncthreads();
#pragma unroll
        for (int j = 0; j < 2; ++j) {
            const uint32_t dv = (uint32_t)dd[j] << 1;
            int p, ss;
            uint32_t b, sl;
            p = iv[j].x; ss = sv[j].x & 1; b = (uint32_t)p >> 5;
            sl = atomicAdd(&curL[b], 1u);
            staging[sl] = ((uint32_t)(p & 31) << 20) | dv | (uint32_t)ss;
            p = iv[j].y; ss = sv[j].y & 1; b = (uint32_t)p >> 5;
            sl = atomicAdd(&curL[b], 1u);
            staging[sl] = ((uint32_t)(p & 31) << 20) | dv | (uint32_t)ss;
            p = iv[j].z; ss = sv[j].z & 1; b = (uint32_t)p >> 5;
            sl = atomicAdd(&curL[b], 1u);
            staging[sl] = ((uint32_t)(p & 31) << 20) | dv | (uint32_t)ss;
            p = iv[j].w; ss = sv[j].w & 1; b = (uint32_t)p >> 5;
            sl = atomicAdd(&curL[b], 1u);
            staging[sl] = ((uint32_t)(p & 31) << 20) | dv | (uint32_t)ss;
        }
        __syncthreads();
        // write chunks coalesced: wave w copies buckets w*16 .. w*16+15
        const int w = t >> 6;
        for (int i = 0; i < NBUCK / 16; ++i) {
            const int b = w * (NBUCK / 16) + i;
            const uint32_t c   = min(cntL[b], (uint32_t)CAPB);
            const uint32_t src = offL[b];
            uint32_t* dst = coarse + ((size_t)b * NBLKA + blk) * CAPB;
            for (uint32_t j2 = lane; j2 < c; j2 += 64) dst[j2] = staging[src + j2];
        }
        if (t < NBUCK) cntAB[(size_t)blk * NBUCK + t] = min(cntL[t], (uint32_t)CAPB);
    } else {
        // ---------------- transpose (256 d per block, 4 tiles of 64) ----
        float* tile = reinterpret_cast<float*>(sh);   // [64][65], 4160 f32
        const int blk   = blockIdx.x - NBLKA;         // 0..2047
        const int dbase = blk * 256;
        const int c  = t & 15;                        // float4 column
        const int r  = t >> 4;                        // batch row 0..63
        const int a  = t & 15;                        // uint2 column (of 16)
        const int dr = t >> 4;                        // d row 0..63
#pragma unroll
        for (int it = 0; it < 4; ++it) {
            const int d0 = dbase + it * 64;
            float4 v = *reinterpret_cast<const float4*>(
                &x[(size_t)r * DIM + d0 + 4 * c]);
            __syncthreads();                  // prev pack done (no-op it=0)
            // bank = (r + 4c + i) % 32 over the wave: 2-way, free
            tile[r * 65 + 4 * c + 0] = v.x;
            tile[r * 65 + 4 * c + 1] = v.y;
            tile[r * 65 + 4 * c + 2] = v.z;
            tile[r * 65 + 4 * c + 3] = v.w;
            __syncthreads();
            // pack: thread -> (d row dr, u32 pair 2a,2a+1); reads rows
            // 4a..4a+3 at col dr; bank = (4a + m + dr) % 32: 2-way, free
            uint32_t lo, hi;
            lo = f2bf(tile[(4 * a + 0) * 65 + dr] * 0.5f);
            hi = f2bf(tile[(4 * a + 1) * 65 + dr] * 0.5f);
            const uint32_t w0 = lo | (hi << 16);
            lo = f2bf(tile[(4 * a + 2) * 65 + dr] * 0.5f);
            hi = f2bf(tile[(4 * a + 3) * 65 + dr] * 0.5f);
            const uint32_t w1 = lo | (hi << 16);
            uint2 wv; wv.x = w0; wv.y = w1;
            // per wave: 4 d-rows x 128B contiguous
            *reinterpret_cast<uint2*>(&xT[(size_t)(d0 + dr) * 32 + 2 * a]) = wv;
        }
    }
}

// ==================== pass 2: fine-bin + gather (half-bucket) ===========
// 512 blocks x 1024 threads; block = half bucket (16 p), 2 blocks/CU.
// Fine-bin: half-wave per chunk; csr row stride CSTR=385 (=1 mod 32) so
// bank = (pl + sl) % 32 -- kills R11's 19.1M same-bank conflicts.
// Gather: wave w -> p_local w (proven inner loop, entries from LDS).
__global__ __launch_bounds__(1024) void gather7_kernel(
    const uint32_t* __restrict__ coarse, const uint32_t* __restrict__ cntAB,
    const uint32_t* __restrict__ xT, float* __restrict__ out)
{
    __shared__ uint32_t csr[16 * CSTR];      // 24,640 B
    __shared__ uint32_t cntF[16];
    __shared__ uint32_t cAB[NBLKA];          // 1 KB
    __shared__ float    obuf[64][17];        // 4,352 B
    const int t       = threadIdx.x;
    const int w       = t >> 6;              // 0..15
    const int lane    = t & 63;
    const int bucket  = blockIdx.x >> 1;
    const int halfsel = blockIdx.x & 1;

    if (t < 16) cntF[t] = 0;
    if (t < NBLKA) cAB[t] = cntAB[(size_t)t * NBUCK + bucket];
    __syncthreads();

    // fine-bin: half-wave hw handles chunks hw*8 .. hw*8+7
    const int hw = t >> 5;                   // 0..31
    const int l  = t & 31;
    for (int i = 0; i < NBLKA / 32; ++i) {
        const int j = hw * (NBLKA / 32) + i;
        const uint32_t c = cAB[j];
        const uint32_t* src = coarse + ((size_t)bucket * NBLKA + j) * CAPB;
        for (uint32_t i2 = l; i2 < c; i2 += 32) {
            const uint32_t pay = src[i2];
            const uint32_t pg  = (pay >> 20) & 31u;
            if ((int)(pg >> 4) == halfsel) {
                const uint32_t pl = pg & 15u;
                const uint32_t sl = atomicAdd(&cntF[pl], 1u);
                csr[pl * CSTR + sl] = pay & 0xFFFFFu;   // d<<1 | s
            }
        }
    }
    __syncthreads();

    // gather: wave w -> p_local w
    const int half = lane >> 5;     // 0: even entries, 1: odd entries
    const int k    = lane & 31;     // u32 index within xT row (2 batch elems)
    const uint32_t n = cntF[w];
    const uint32_t* e = &csr[w * CSTR];
    float acc0 = 0.f, acc1 = 0.f;
    uint32_t base = 0;
    for (; base + 8 <= n; base += 8) {
        uint32_t e8[8];
#pragma unroll
        for (int q = 0; q < 8; ++q) e8[q] = e[base + q];
#pragma unroll
        for (int q = 0; q < 8; q += 2) {
            uint32_t sel = half ? e8[q + 1] : e8[q];
            uint32_t u = xT[(size_t)(sel >> 1) * 32 + k];  // 128B/half-wave
            u ^= (sel & 1u) ? 0u : 0x80008000u;            // s=0 -> negate
            acc0 += __uint_as_float(u << 16);              // b = 2k
            acc1 += __uint_as_float(u & 0xffff0000u);      // b = 2k+1
        }
    }
    for (; base < n; base += 2) {
        uint32_t eA = e[base];
        uint32_t eB = (base + 1 < n) ? e[base + 1] : 0u;
        uint32_t sel   = half ? eB : eA;
        bool     valid = (base + (uint32_t)half) < n;
        uint32_t u = 0u;
        if (valid) {
            u = xT[(size_t)(sel >> 1) * 32 + k];
            u ^= (sel & 1u) ? 0u : 0x80008000u;
        }
        acc0 += __uint_as_float(u << 16);
        acc1 += __uint_as_float(u & 0xffff0000u);
    }
    acc0 += __shfl_xor(acc0, 32);
    acc1 += __shfl_xor(acc1, 32);
    if (half == 0) {
        obuf[2 * k + 0][w] = acc0;
        obuf[2 * k + 1][w] = acc1;
    }
    __syncthreads();
    // out: 64 rows x 16 p = one full 64B line per row
    if (t < 256) {
        const int b = t >> 2, q = t & 3;
        float4 vv;
        vv.x = obuf[b][4 * q + 0];
        vv.y = obuf[b][4 * q + 1];
        vv.z = obuf[b][4 * q + 2];
        vv.w = obuf[b][4 * q + 3];
        *reinterpret_cast<float4*>(
            &out[(size_t)b * PROJ + bucket * BUCKP + halfsel * 16 + 4 * q]) = vv;
    }
}

// ==================== R9 fallback: fused scatter + gather4 ==============
__global__ __launch_bounds__(256) void fused_tx_scatter(
    const float* __restrict__ x, const int* __restrict__ idx,
    const int* __restrict__ sgn, uint32_t* __restrict__ cnt,
    uint32_t* __restrict__ entries, uint32_t* __restrict__ xT)
{
    __shared__ float tile[64][65];
    const int d0 = blockIdx.x * 64;
    const int t  = threadIdx.x;

    const int e = (d0 << 2) + t;
    const int p = idx[e];
    const int s = sgn[e] & 1;

    const int c  = t & 15;
    const int r0 = t >> 4;
    float4 v[4];
#pragma unroll
    for (int it = 0; it < 4; ++it) {
        int b = it * 16 + r0;
        v[it] = *reinterpret_cast<const float4*>(&x[(size_t)b * DIM + d0 + 4 * c]);
    }
    {
        uint32_t dv   = ((uint32_t)(d0 + (t >> 2)) << 1) | (uint32_t)s;
        uint32_t slot = atomicAdd(&cnt[p], 1u);
        entries[(uint32_t)p * (uint32_t)CAP + slot] = dv;
    }
#pragma unroll
    for (int it = 0; it < 4; ++it) {
        int b = it * 16 + r0;
        tile[b][4 * c + 0] = v[it].x;
        tile[b][4 * c + 1] = v[it].y;
        tile[b][4 * c + 2] = v[it].z;
        tile[b][4 * c + 3] = v[it].w;
    }
    __syncthreads();
    const int a  = t & 7;
    const int dr = t >> 3;
#pragma unroll
    for (int pass = 0; pass < 2; ++pass) {
        const int dl = pass * 32 + dr;
        uint4 wv;
        uint32_t* wq = reinterpret_cast<uint32_t*>(&wv);
#pragma unroll
        for (int q = 0; q < 4; ++q) {
            const int k = 4 * a + q;
            uint32_t lo = f2bf(tile[2 * k + 0][dl] * 0.5f);
            uint32_t hi = f2bf(tile[2 * k + 1][dl] * 0.5f);
            wq[q] = lo | (hi << 16);
        }
        *reinterpret_cast<uint4*>(&xT[(size_t)(d0 + dl) * 32 + 4 * a]) = wv;
    }
}

__device__ __forceinline__ void proc8(const uint32_t* __restrict__ e,
    const uint32_t* __restrict__ xT, int half, int k,
    float& acc0, float& acc1)
{
#pragma unroll
    for (int t = 0; t < 8; t += 2) {
        uint32_t sel = half ? e[t + 1] : e[t];
        uint32_t u = xT[(size_t)(sel >> 1) * 32 + k];
        u ^= (sel & 1u) ? 0u : 0x80008000u;
        acc0 += __uint_as_float(u << 16);
        acc1 += __uint_as_float(u & 0xffff0000u);
    }
}

__global__ __launch_bounds__(1024) void gather4_kernel(
    const uint32_t* __restrict__ entries, const uint32_t* __restrict__ cnt,
    const uint32_t* __restrict__ xT, float* __restrict__ out)
{
    __shared__ float obuf[64][17];
    const int w    = threadIdx.x >> 6;
    const int lane = threadIdx.x & 63;
    const int p    = __builtin_amdgcn_readfirstlane(blockIdx.x * 16 + w);
    const uint32_t n  = __builtin_amdgcn_readfirstlane(cnt[p]);
    const uint32_t e0 = (uint32_t)p * (uint32_t)CAP;

    const int half = lane >> 5;
    const int k    = lane & 31;
    float acc0 = 0.f, acc1 = 0.f;

    uint32_t A[8], B[8];
    uint32_t base = 0;
    if (n >= 8) {
#pragma unroll
        for (int t = 0; t < 8; ++t) A[t] = entries[e0 + t];
    }
    for (; base + 24 <= n; base += 16) {
#pragma unroll
        for (int t = 0; t < 8; ++t) B[t] = entries[e0 + base + 8 + t];
        proc8(A, xT, half, k, acc0, acc1);
#pragma unroll
        for (int t = 0; t < 8; ++t) A[t] = entries[e0 + base + 16 + t];
        proc8(B, xT, half, k, acc0, acc1);
    }
    if (base + 16 <= n) {
#pragma unroll
        for (int t = 0; t < 8; ++t) B[t] = entries[e0 + base + 8 + t];
        proc8(A, xT, half, k, acc0, acc1);
        proc8(B, xT, half, k, acc0, acc1);
        base += 16;
    } else if (base + 8 <= n) {
        proc8(A, xT, half, k, acc0, acc1);
        base += 8;
    }
    for (; base < n; base += 2) {
        uint32_t eA = entries[e0 + base];
        uint32_t eB = (base + 1 < n) ? entries[e0 + base + 1] : 0u;
        uint32_t sel   = half ? eB : eA;
        bool     valid = (base + (uint32_t)half) < n;
        uint32_t u = 0u;
        if (valid) {
            u = xT[(size_t)(sel >> 1) * 32 + k];
            u ^= (sel & 1u) ? 0u : 0x80008000u;
        }
        acc0 += __uint_as_float(u << 16);
        acc1 += __uint_as_float(u & 0xffff0000u);
    }
    acc0 += __shfl_xor(acc0, 32);
    acc1 += __shfl_xor(acc1, 32);
    if (half == 0) {
        obuf[2 * k + 0][w] = acc0;
        obuf[2 * k + 1][w] = acc1;
    }
    __syncthreads();
    const int t = threadIdx.x;
    if (t < 256) {
        const int b = t >> 2, q = t & 3;
        float4 v;
        v.x = obuf[b][4 * q + 0];
        v.y = obuf[b][4 * q + 1];
        v.z = obuf[b][4 * q + 2];
        v.w = obuf[b][4 * q + 3];
        *reinterpret_cast<float4*>(&out[(size_t)b * PROJ + blockIdx.x * 16 + 4 * q]) = v;
    }
}

// ------------------------------------------------- fallback (R3 scatter)
__device__ __forceinline__ void lds_fadd(uint32_t byte_addr, float v) {
    asm volatile("ds_add_f32 %0, %1" :: "v"(byte_addr), "v"(v) : "memory");
}
__device__ __forceinline__ void lds_fadd_off32k(uint32_t byte_addr, float v) {
    asm volatile("ds_add_f32 %0, %1 offset:32768" :: "v"(byte_addr), "v"(v) : "memory");
}

__global__ __launch_bounds__(1024) void sjlt_scatter(
    const float* __restrict__ x, const int4* __restrict__ idx4,
    const int4* __restrict__ sgn4, float* __restrict__ out)
{
    __shared__ float acc[4 * PROJ];
    for (int i = threadIdx.x; i < 4 * PROJ; i += 1024) acc[i] = 0.0f;
    __syncthreads();
    const int row0 = blockIdx.y * 4;
    const int dbeg = blockIdx.x * (DIM / 16);
    const uint32_t accBase = (uint32_t)(uintptr_t)(&acc[0]);
    const float* xr0 = x + (size_t)(row0 + 0) * DIM;
    const float* xr1 = x + (size_t)(row0 + 1) * DIM;
    const float* xr2 = x + (size_t)(row0 + 2) * DIM;
    const float* xr3 = x + (size_t)(row0 + 3) * DIM;
    for (int d = dbeg + (int)threadIdx.x; d < dbeg + DIM / 16; d += 1024) {
        const int4 iv = idx4[d];
        const int4 sv = sgn4[d];
        const uint32_t u0 = __float_as_uint(xr0[d]);
        const uint32_t u1 = __float_as_uint(xr1[d]);
        const uint32_t u2 = __float_as_uint(xr2[d]);
        const uint32_t u3 = __float_as_uint(xr3[d]);
        const int p[4] = {iv.x, iv.y, iv.z, iv.w};
        const int s[4] = {sv.x, sv.y, sv.z, sv.w};
#pragma unroll
        for (int j = 0; j < 4; ++j) {
            const uint32_t flip = (uint32_t)(s[j] ^ 1) << 31;
            const uint32_t a01  = accBase + ((uint32_t)p[j] << 2);
            const uint32_t a23  = a01 + 2u * 32768u;
            lds_fadd        (a01, __uint_as_float(u0 ^ flip));
            lds_fadd_off32k (a01, __uint_as_float(u1 ^ flip));
            lds_fadd        (a23, __uint_as_float(u2 ^ flip));
            lds_fadd_off32k (a23, __uint_as_float(u3 ^ flip));
        }
    }
    __syncthreads();
    for (int i = threadIdx.x; i < 4 * PROJ; i += 1024) {
        const int r  = i >> 13;
        const int pp = i & (PROJ - 1);
        unsafeAtomicAdd(&out[(size_t)(row0 + r) * PROJ + pp], acc[i] * 0.5f);
    }
}

// --------------------------------------------------------------- launch
extern "C" void kernel_launch(void* const* d_in, const int* in_sizes, int n_in,
                              void* d_out, int out_size, void* d_ws, size_t ws_size,
                              hipStream_t stream) {
    const float* x   = (const float*)d_in[0];
    const int4*  idx = (const int4*) d_in[1];
    const int4*  sgn = (const int4*) d_in[2];
    float*       out = (float*)d_out;

    // R12 layout: cntAB[256*256] | coarse[256*256*80] | xT[DIM*32] = 88,342,528 B
    const size_t need_r12 = ((size_t)NBLKA * NBUCK
                           + (size_t)NBUCK * NBLKA * CAPB
                           + (size_t)DIM * 32) * 4;
    // R9 layout: cnt[PROJ] | entries[PROJ*CAP] | xT[DIM*32]       = 79,724,544 B
    const size_t need_r9  = ((size_t)PROJ + (size_t)PROJ * CAP + (size_t)DIM * 32) * 4;

    if (ws_size >= need_r12) {
        uint32_t* cntAB  = (uint32_t*)d_ws;
        uint32_t* coarse = cntAB + (size_t)NBLKA * NBUCK;
        uint32_t* xT     = coarse + (size_t)NBUCK * NBLKA * CAPB;

        // no memsets: cntAB fully written by prep (binA part); LDS counters
        // zeroed in-kernel; coarse padding beyond counts never read.
        prep_kernel   <<<NBLKA + TBLK, 1024, 0, stream>>>(
            x, idx, sgn, cntAB, coarse, xT);
        gather7_kernel<<<NBUCK * 2,    1024, 0, stream>>>(coarse, cntAB, xT, out);
    } else if (ws_size >= need_r9) {
        uint32_t* cnt     = (uint32_t*)d_ws;
        uint32_t* entries = cnt + PROJ;
        uint32_t* xT      = entries + (size_t)PROJ * CAP;

        hipMemsetAsync(cnt, 0, PROJ * sizeof(uint32_t), stream);
        fused_tx_scatter<<<DIM / 64, 256, 0, stream>>>(
            x, (const int*)idx, (const int*)sgn, cnt, entries, xT);
        gather4_kernel<<<PROJ / 16, 1024, 0, stream>>>(entries, cnt, xT, out);
    } else {
        // ws too small: R3 LDS-scatter path (passes at ~830 us)
        hipMemsetAsync(d_out, 0, (size_t)out_size * sizeof(float), stream);
        dim3 grid(16, 16);
        sjlt_scatter<<<grid, 1024, 0, stream>>>(x, idx, sgn, out);
    }
}

// Round 7
// 309.860 us; speedup vs baseline: 1.0263x; 1.0263x over previous
//
#include <hip/hip_runtime.h>

// SJLT projection: out[b, idx[d,j]] += x[b,d] * sign(d,j), * 1/sqrt(4)
// B=64, D=524288, P=8192, C=4.
//
// Model so far (R1-R12):
//  - Random 4B global stores: 64B HBM write-back EACH. L2 no-write-allocate;
//    pretouch does NOT help (R9); spatial partitioning does NOT help (R8).
//    => only LDS-staged coalesced chunk writes avoid the 10x inflation.
//  - Harness re-poisons the full ws INSIDE the timed region: fillBuffer
//    = 82 us/iter (R11). Floor ~= 82 + launches + our kernels.
//  - R11/R12: gather's 19.1M LDS bank conflicts are NOT csr-write stride
//    (R12 falsified: stride change left count identical) -- they are the
//    fine-bin atomicAdd(&cntF[pl]) same-address serialization (16 fixed
//    banks). Also CSTR=385 broke 16B alignment of csr rows -> no
//    ds_read_b128 -> gather7 81->96.7 us regression.
// R13: zero-atomic fine-bin. binA bins to 512 DENSE half-bucket streams
// (global base via one atomicAdd per (hb, block); no padding, no cntAB).
// gather8: wave reads its segment into registers, two-phase ballot
// counting sort (A: ballot+popc counts; LDS scan -> deterministic bases;
// B: place at base+rank), CSTR=388 (16B-aligned, 4 mod 32) restores
// ds_read_b128. Zero LDS atomics in the whole kernel.

constexpr int BATCH = 64;
constexpr int DIM   = 524288;
constexpr int PROJ  = 8192;
constexpr int NENT  = DIM * 4;          // 2,097,152 entries
constexpr int CAP   = 384;              // per-p entry cap (proven R7-R12)
constexpr int CSTR  = 388;              // csr row stride: 16B-aligned, =4 mod 32

constexpr int NBLKA = 256;              // binA blocks
constexpr int EPB   = NENT / NBLKA;     // 8192 entries per binA block
constexpr int NHB   = 512;              // half-buckets
constexpr int HBP   = PROJ / NHB;       // 16 p per half-bucket
constexpr int CAPH  = 4608;             // dense cap per hb: mean 4096 + 8 sigma
constexpr int TBLK  = 2048;             // transpose blocks (256 d each)
constexpr int MAXR  = 5;                // max rounds: ceil((CAPH/16)/64) = 5

// ------------------------------------------------ helpers
__device__ __forceinline__ uint32_t f2bf(float f) {   // RNE f32 -> bf16 bits
    uint32_t u = __float_as_uint(f);
    return (u + 0x7fffu + ((u >> 16) & 1u)) >> 16;
}

// ==================== pass 1: fused binA + transpose ====================
// Blocks [0,256): binA -- count/scan/compact 8192 entries into 512
// half-bucket groups in LDS, then append each group DENSELY to its global
// stream at base = atomicAdd(&gBase[hb], cnt). Payload: (p&15)<<20|d<<1|s.
// Blocks [256,2304): transpose -- 256 d's each, x -> bf16-pair xT rows.
__global__ __launch_bounds__(1024) void prep_kernel(
    const float* __restrict__ x, const int4* __restrict__ idx4,
    const int4* __restrict__ sgn4, uint32_t* __restrict__ gBase,
    uint32_t* __restrict__ dense, uint32_t* __restrict__ xT)
{
    __shared__ uint32_t sh[10260];       // 41,040 B, unioned
    const int t = threadIdx.x;

    if (blockIdx.x < NBLKA) {
        // ---------------- binA ----------------
        uint32_t* cntL    = sh;          // 512
        uint32_t* offL    = sh + 512;    // 512
        uint32_t* curL    = sh + 1024;   // 512
        uint32_t* wsum    = sh + 1536;   // 8
        uint32_t* gb      = sh + 1544;   // 512
        uint32_t* staging = sh + 2056;   // 8192 (32 KB)
        const int lane = t & 63;
        const int blk  = blockIdx.x;

        if (t < NHB) cntL[t] = 0;
        __syncthreads();

        int4 iv[2], sv[2];
        int  dd[2];
#pragma unroll
        for (int j = 0; j < 2; ++j) {
            int d = blk * 2048 + j * 1024 + t;
            dd[j] = d;
            iv[j] = idx4[d];
            sv[j] = sgn4[d];
        }
#pragma unroll
        for (int j = 0; j < 2; ++j) {
            atomicAdd(&cntL[(uint32_t)iv[j].x >> 4], 1u);
            atomicAdd(&cntL[(uint32_t)iv[j].y >> 4], 1u);
            atomicAdd(&cntL[(uint32_t)iv[j].z >> 4], 1u);
            atomicAdd(&cntL[(uint32_t)iv[j].w >> 4], 1u);
        }
        __syncthreads();
        // exclusive scan of cntL[512] (first 8 waves)
        uint32_t v = 0, s = 0;
        if (t < NHB) {
            s = cntL[t]; v = s;
#pragma unroll
            for (int off = 1; off < 64; off <<= 1) {
                uint32_t u = __shfl_up(v, off);
                if (lane >= off) v += u;
            }
            if (lane == 63) wsum[t >> 6] = v;
        }
        __syncthreads();
        if (t < NHB) {
            uint32_t wb = 0;
            for (int w0 = 0; w0 < (t >> 6); ++w0) wb += wsum[w0];
            uint32_t ex = wb + v - s;
            offL[t] = ex;
            curL[t] = ex;
        }
        __syncthreads();
#pragma unroll
        for (int j = 0; j < 2; ++j) {
            const uint32_t dv = (uint32_t)dd[j] << 1;
            int p, ss;
            uint32_t b, sl;
            p = iv[j].x; ss = sv[j].x & 1; b = (uint32_t)p >> 4;
            sl = atomicAdd(&curL[b], 1u);
            staging[sl] = ((uint32_t)(p & 15) << 20) | dv | (uint32_t)ss;
            p = iv[j].y; ss = sv[j].y & 1; b = (uint32_t)p >> 4;
            sl = atomicAdd(&curL[b], 1u);
            staging[sl] = ((uint32_t)(p & 15) << 20) | dv | (uint32_t)ss;
            p = iv[j].z; ss = sv[j].z & 1; b = (uint32_t)p >> 4;
            sl = atomicAdd(&curL[b], 1u);
            staging[sl] = ((uint32_t)(p & 15) << 20) | dv | (uint32_t)ss;
            p = iv[j].w; ss = sv[j].w & 1; b = (uint32_t)p >> 4;
            sl = atomicAdd(&curL[b], 1u);
            staging[sl] = ((uint32_t)(p & 15) << 20) | dv | (uint32_t)ss;
        }
        __syncthreads();
        // global dense base per half-bucket (device-scope atomic)
        if (t < NHB) gb[t] = atomicAdd(&gBase[t], cntL[t]);
        __syncthreads();
        // append groups densely: wave w copies hb = w*32 .. w*32+31
        const int w = t >> 6;
        for (int i = 0; i < NHB / 16; ++i) {
            const int b = w * (NHB / 16) + i;
            const uint32_t c   = cntL[b];
            const uint32_t src = offL[b];
            const uint32_t g0  = gb[b];
            const uint32_t lim = (g0 < (uint32_t)CAPH) ? ((uint32_t)CAPH - g0) : 0u;
            const uint32_t cw  = c < lim ? c : lim;
            uint32_t* dst = dense + (size_t)b * CAPH + g0;
            for (uint32_t j2 = lane; j2 < cw; j2 += 64) dst[j2] = staging[src + j2];
        }
    } else {
        // ---------------- transpose (256 d per block, 4 tiles of 64) ----
        float* tile = reinterpret_cast<float*>(sh);   // [64][65], 4160 f32
        const int blk   = blockIdx.x - NBLKA;         // 0..2047
        const int dbase = blk * 256;
        const int c  = t & 15;                        // float4 column
        const int r  = t >> 4;                        // batch row 0..63
        const int a  = t & 15;                        // uint2 column (of 16)
        const int dr = t >> 4;                        // d row 0..63
#pragma unroll
        for (int it = 0; it < 4; ++it) {
            const int d0 = dbase + it * 64;
            float4 v = *reinterpret_cast<const float4*>(
                &x[(size_t)r * DIM + d0 + 4 * c]);
            __syncthreads();                  // prev pack done (no-op it=0)
            tile[r * 65 + 4 * c + 0] = v.x;
            tile[r * 65 + 4 * c + 1] = v.y;
            tile[r * 65 + 4 * c + 2] = v.z;
            tile[r * 65 + 4 * c + 3] = v.w;
            __syncthreads();
            uint32_t lo, hi;
            lo = f2bf(tile[(4 * a + 0) * 65 + dr] * 0.5f);
            hi = f2bf(tile[(4 * a + 1) * 65 + dr] * 0.5f);
            const uint32_t w0 = lo | (hi << 16);
            lo = f2bf(tile[(4 * a + 2) * 65 + dr] * 0.5f);
            hi = f2bf(tile[(4 * a + 3) * 65 + dr] * 0.5f);
            const uint32_t w1 = lo | (hi << 16);
            uint2 wv; wv.x = w0; wv.y = w1;
            *reinterpret_cast<uint2*>(&xT[(size_t)(d0 + dr) * 32 + 2 * a]) = wv;
        }
    }
}

// ==================== pass 2: counting-sort fine-bin + gather ===========
// 512 blocks x 1024 threads; block = half-bucket (16 p), 2 blocks/CU.
// Wave w reads its 1/16 segment of the dense stream into registers (<=5
// rounds), then: phase A ballot-counts per pl; LDS scan -> deterministic
// bases; phase B places each entry at base+rank. NO LDS atomics anywhere.
// Gather: wave w -> p_local w (proven 8-unroll, ds_read_b128-aligned rows).
__global__ __launch_bounds__(1024) void gather8_kernel(
    const uint32_t* __restrict__ dense, const uint32_t* __restrict__ gBase,
    const uint32_t* __restrict__ xT, float* __restrict__ out)
{
    __shared__ uint32_t csr[16 * CSTR];      // 24,832 B
    __shared__ uint32_t wcnt[16][16];        // [wave][pl]
    __shared__ uint32_t baseL[16][16];       // [wave][pl]
    __shared__ uint32_t cntF[16];
    __shared__ float    obuf[64][17];        // 4,352 B
    const int t    = threadIdx.x;
    const int w    = t >> 6;                 // 0..15
    const int lane = t & 63;
    const int hb   = blockIdx.x;             // half-bucket 0..511

    uint32_t nt = gBase[hb];
    if (nt > (uint32_t)CAPH) nt = (uint32_t)CAPH;
    const uint32_t* src = dense + (size_t)hb * CAPH;
    const uint32_t s0 = (nt * (uint32_t)w) >> 4;
    const uint32_t s1 = (nt * (uint32_t)(w + 1)) >> 4;

    // ---- phase A: load segment into registers + ballot counts ----
    uint32_t pay[MAXR];
    uint32_t c16[16];
#pragma unroll
    for (int q = 0; q < 16; ++q) c16[q] = 0;
#pragma unroll
    for (int r = 0; r < MAXR; ++r) {
        const uint32_t i2 = s0 + (uint32_t)(r * 64 + lane);
        const bool ok = i2 < s1;
        pay[r] = ok ? src[i2] : 0xFFFFFFFFu;     // pv decodes to 99 below
        const uint32_t pv = ok ? ((pay[r] >> 20) & 15u) : 99u;
#pragma unroll
        for (int q = 0; q < 16; ++q) {
            const unsigned long long m = __ballot(pv == (uint32_t)q);
            c16[q] += (uint32_t)__popcll(m);     // wave-uniform
        }
    }
    if (lane == 0) {
#pragma unroll
        for (int q = 0; q < 16; ++q) wcnt[w][q] = c16[q];
    }
    __syncthreads();
    // ---- bases: baseL[w][q] = q*CSTR + sum_{w'<w} wcnt[w'][q] ----
    if (t < 256) {
        const int w2 = t >> 4, q2 = t & 15;
        uint32_t acc = 0;
        for (int wp = 0; wp < w2; ++wp) acc += wcnt[wp][q2];
        baseL[w2][q2] = (uint32_t)(q2 * CSTR) + acc;
        if (w2 == 15) cntF[q2] = acc + wcnt[15][q2];
    }
    __syncthreads();
    // ---- phase B: place at base + rank (deterministic, no atomics) ----
    uint32_t rb[16];
#pragma unroll
    for (int q = 0; q < 16; ++q) rb[q] = baseL[w][q];
    const unsigned long long below = ((unsigned long long)1 << lane) - 1ull;
#pragma unroll
    for (int r = 0; r < MAXR; ++r) {
        const uint32_t i2 = s0 + (uint32_t)(r * 64 + lane);
        const bool ok = i2 < s1;
        const uint32_t pv = ok ? ((pay[r] >> 20) & 15u) : 99u;
        uint32_t slot = 0xFFFFFFFFu;
#pragma unroll
        for (int q = 0; q < 16; ++q) {
            const unsigned long long m = __ballot(pv == (uint32_t)q);
            if (pv == (uint32_t)q) slot = rb[q] + (uint32_t)__popcll(m & below);
            rb[q] += (uint32_t)__popcll(m);      // wave-uniform
        }
        if (slot < (uint32_t)(16 * CSTR)) csr[slot] = pay[r] & 0xFFFFFu;
    }
    __syncthreads();

    // ---- gather: wave w -> p_local w ----
    const int half = lane >> 5;     // 0: even entries, 1: odd entries
    const int k    = lane & 31;     // u32 index within xT row (2 batch elems)
    const uint32_t n = cntF[w];
    const uint32_t* e = &csr[w * CSTR];      // 16B-aligned (CSTR = 97*4)
    float acc0 = 0.f, acc1 = 0.f;
    uint32_t base = 0;
    for (; base + 8 <= n; base += 8) {
        uint32_t e8[8];
#pragma unroll
        for (int q = 0; q < 8; ++q) e8[q] = e[base + q];
#pragma unroll
        for (int q = 0; q < 8; q += 2) {
            uint32_t sel = half ? e8[q + 1] : e8[q];
            uint32_t u = xT[(size_t)(sel >> 1) * 32 + k];  // 128B/half-wave
            u ^= (sel & 1u) ? 0u : 0x80008000u;            // s=0 -> negate
            acc0 += __uint_as_float(u << 16);              // b = 2k
            acc1 += __uint_as_float(u & 0xffff0000u);      // b = 2k+1
        }
    }
    for (; base < n; base += 2) {
        uint32_t eA = e[base];
        uint32_t eB = (base + 1 < n) ? e[base + 1] : 0u;
        uint32_t sel   = half ? eB : eA;
        bool     valid = (base + (uint32_t)half) < n;
        uint32_t u = 0u;
        if (valid) {
            u = xT[(size_t)(sel >> 1) * 32 + k];
            u ^= (sel & 1u) ? 0u : 0x80008000u;
        }
        acc0 += __uint_as_float(u << 16);
        acc1 += __uint_as_float(u & 0xffff0000u);
    }
    acc0 += __shfl_xor(acc0, 32);
    acc1 += __shfl_xor(acc1, 32);
    if (half == 0) {
        obuf[2 * k + 0][w] = acc0;
        obuf[2 * k + 1][w] = acc1;
    }
    __syncthreads();
    // out: 64 rows x 16 p = one full 64B line per row
    if (t < 256) {
        const int b = t >> 2, q = t & 3;
        float4 vv;
        vv.x = obuf[b][4 * q + 0];
        vv.y = obuf[b][4 * q + 1];
        vv.z = obuf[b][4 * q + 2];
        vv.w = obuf[b][4 * q + 3];
        *reinterpret_cast<float4*>(
            &out[(size_t)b * PROJ + hb * HBP + 4 * q]) = vv;
    }
}

// ------------------------------------------------- fallback (R3 scatter)
__device__ __forceinline__ void lds_fadd(uint32_t byte_addr, float v) {
    asm volatile("ds_add_f32 %0, %1" :: "v"(byte_addr), "v"(v) : "memory");
}
__device__ __forceinline__ void lds_fadd_off32k(uint32_t byte_addr, float v) {
    asm volatile("ds_add_f32 %0, %1 offset:32768" :: "v"(byte_addr), "v"(v) : "memory");
}

__global__ __launch_bounds__(1024) void sjlt_scatter(
    const float* __restrict__ x, const int4* __restrict__ idx4,
    const int4* __restrict__ sgn4, float* __restrict__ out)
{
    __shared__ float acc[4 * PROJ];
    for (int i = threadIdx.x; i < 4 * PROJ; i += 1024) acc[i] = 0.0f;
    __syncthreads();
    const int row0 = blockIdx.y * 4;
    const int dbeg = blockIdx.x * (DIM / 16);
    const uint32_t accBase = (uint32_t)(uintptr_t)(&acc[0]);
    const float* xr0 = x + (size_t)(row0 + 0) * DIM;
    const float* xr1 = x + (size_t)(row0 + 1) * DIM;
    const float* xr2 = x + (size_t)(row0 + 2) * DIM;
    const float* xr3 = x + (size_t)(row0 + 3) * DIM;
    for (int d = dbeg + (int)threadIdx.x; d < dbeg + DIM / 16; d += 1024) {
        const int4 iv = idx4[d];
        const int4 sv = sgn4[d];
        const uint32_t u0 = __float_as_uint(xr0[d]);
        const uint32_t u1 = __float_as_uint(xr1[d]);
        const uint32_t u2 = __float_as_uint(xr2[d]);
        const uint32_t u3 = __float_as_uint(xr3[d]);
        const int p[4] = {iv.x, iv.y, iv.z, iv.w};
        const int s[4] = {sv.x, sv.y, sv.z, sv.w};
#pragma unroll
        for (int j = 0; j < 4; ++j) {
            const uint32_t flip = (uint32_t)(s[j] ^ 1) << 31;
            const uint32_t a01  = accBase + ((uint32_t)p[j] << 2);
            const uint32_t a23  = a01 + 2u * 32768u;
            lds_fadd        (a01, __uint_as_float(u0 ^ flip));
            lds_fadd_off32k (a01, __uint_as_float(u1 ^ flip));
            lds_fadd        (a23, __uint_as_float(u2 ^ flip));
            lds_fadd_off32k (a23, __uint_as_float(u3 ^ flip));
        }
    }
    __syncthreads();
    for (int i = threadIdx.x; i < 4 * PROJ; i += 1024) {
        const int r  = i >> 13;
        const int pp = i & (PROJ - 1);
        unsafeAtomicAdd(&out[(size_t)(row0 + r) * PROJ + pp], acc[i] * 0.5f);
    }
}

// --------------------------------------------------------------- launch
extern "C" void kernel_launch(void* const* d_in, const int* in_sizes, int n_in,
                              void* d_out, int out_size, void* d_ws, size_t ws_size,
                              hipStream_t stream) {
    const float* x   = (const float*)d_in[0];
    const int4*  idx = (const int4*) d_in[1];
    const int4*  sgn = (const int4*) d_in[2];
    float*       out = (float*)d_out;

    // R13 layout: gBase[512] | dense[512*4608] | xT[DIM*32] = 76,548,096 B
    const size_t need_r13 = ((size_t)NHB + (size_t)NHB * CAPH + (size_t)DIM * 32) * 4;

    if (ws_size >= need_r13) {
        uint32_t* gBase = (uint32_t*)d_ws;
        uint32_t* dense = gBase + NHB;
        uint32_t* xT    = dense + (size_t)NHB * CAPH;

        hipMemsetAsync(gBase, 0, NHB * sizeof(uint32_t), stream);  // 2 KB
        prep_kernel   <<<NBLKA + TBLK, 1024, 0, stream>>>(
            x, idx, sgn, gBase, dense, xT);
        gather8_kernel<<<NHB,          1024, 0, stream>>>(dense, gBase, xT, out);
    } else {
        // ws too small: R3 LDS-scatter path (passes at ~830 us)
        hipMemsetAsync(d_out, 0, (size_t)out_size * sizeof(float), stream);
        dim3 grid(16, 16);
        sjlt_scatter<<<grid, 1024, 0, stream>>>(x, idx, sgn, out);
    }
}

// Round 8
// 295.914 us; speedup vs baseline: 1.0747x; 1.0471x over previous
//
#include <hip/hip_runtime.h>

// SJLT projection: out[b, idx[d,j]] += x[b,d] * sign(d,j), * 1/sqrt(4)
// B=64, D=524288, P=8192, C=4.
//
// Model so far (R1-R13):
//  - Random 4B global stores: 64B HBM write-back EACH. L2 no-write-allocate;
//    pretouch (R9) and spatial partitioning (R8) do NOT help. Only LDS-staged
//    coalesced chunk writes avoid the ~10x inflation.
//  - Harness re-poisons the full ws INSIDE the timed region: fillBuffer
//    = 82 us/iter (R11). Floor ~= 82 + launches + our kernels.
//  - SQ_LDS_BANK_CONFLICT (~19M) does NOT correlate with gather duration
//    (gather5: 0.37M/107us vs gather6: 19M/81us) -- stop chasing it.
//  - Gather ranking by time: direct-stream, no fine-bin (gather4, 65us)
//    beats every LDS pre-sort variant (81-107us). Fine-bin is pure loss.
// R14: prep (R13, proven: fused transpose + binA -> 512 dense half-bucket
// streams) + gather9: NO fine-bin. Wave streams a contiguous segment of
// the unsorted hb stream; 16 register accumulator pairs; routing via
// switch(readfirstlane(pv)) -- wave-uniform scalar branch, compile-time
// acc indices, zero LDS in the hot loop. 4-round LDS tree-reduce across
// waves at the end; full-line out writes.

constexpr int BATCH = 64;
constexpr int DIM   = 524288;
constexpr int PROJ  = 8192;
constexpr int NENT  = DIM * 4;          // 2,097,152 entries
constexpr int NBLKA = 256;              // binA blocks
constexpr int EPB   = NENT / NBLKA;     // 8192 entries per binA block
constexpr int NHB   = 512;              // half-buckets
constexpr int HBP   = PROJ / NHB;       // 16 p per half-bucket
constexpr int CAPH  = 4608;             // dense cap per hb: mean 4096 + 8 sigma
constexpr int TBLK  = 2048;             // transpose blocks (256 d each)

// ------------------------------------------------ helpers
__device__ __forceinline__ uint32_t f2bf(float f) {   // RNE f32 -> bf16 bits
    uint32_t u = __float_as_uint(f);
    return (u + 0x7fffu + ((u >> 16) & 1u)) >> 16;
}

// ==================== pass 1: fused binA + transpose (R13, proven) ======
__global__ __launch_bounds__(1024) void prep_kernel(
    const float* __restrict__ x, const int4* __restrict__ idx4,
    const int4* __restrict__ sgn4, uint32_t* __restrict__ gBase,
    uint32_t* __restrict__ dense, uint32_t* __restrict__ xT)
{
    __shared__ uint32_t sh[10260];       // 41,040 B, unioned
    const int t = threadIdx.x;

    if (blockIdx.x < NBLKA) {
        // ---------------- binA ----------------
        uint32_t* cntL    = sh;          // 512
        uint32_t* offL    = sh + 512;    // 512
        uint32_t* curL    = sh + 1024;   // 512
        uint32_t* wsum    = sh + 1536;   // 8
        uint32_t* gb      = sh + 1544;   // 512
        uint32_t* staging = sh + 2056;   // 8192 (32 KB)
        const int lane = t & 63;
        const int blk  = blockIdx.x;

        if (t < NHB) cntL[t] = 0;
        __syncthreads();

        int4 iv[2], sv[2];
        int  dd[2];
#pragma unroll
        for (int j = 0; j < 2; ++j) {
            int d = blk * 2048 + j * 1024 + t;
            dd[j] = d;
            iv[j] = idx4[d];
            sv[j] = sgn4[d];
        }
#pragma unroll
        for (int j = 0; j < 2; ++j) {
            atomicAdd(&cntL[(uint32_t)iv[j].x >> 4], 1u);
            atomicAdd(&cntL[(uint32_t)iv[j].y >> 4], 1u);
            atomicAdd(&cntL[(uint32_t)iv[j].z >> 4], 1u);
            atomicAdd(&cntL[(uint32_t)iv[j].w >> 4], 1u);
        }
        __syncthreads();
        // exclusive scan of cntL[512] (first 8 waves)
        uint32_t v = 0, s = 0;
        if (t < NHB) {
            s = cntL[t]; v = s;
#pragma unroll
            for (int off = 1; off < 64; off <<= 1) {
                uint32_t u = __shfl_up(v, off);
                if (lane >= off) v += u;
            }
            if (lane == 63) wsum[t >> 6] = v;
        }
        __syncthreads();
        if (t < NHB) {
            uint32_t wb = 0;
            for (int w0 = 0; w0 < (t >> 6); ++w0) wb += wsum[w0];
            uint32_t ex = wb + v - s;
            offL[t] = ex;
            curL[t] = ex;
        }
        __syncthreads();
#pragma unroll
        for (int j = 0; j < 2; ++j) {
            const uint32_t dv = (uint32_t)dd[j] << 1;
            int p, ss;
            uint32_t b, sl;
            p = iv[j].x; ss = sv[j].x & 1; b = (uint32_t)p >> 4;
            sl = atomicAdd(&curL[b], 1u);
            staging[sl] = ((uint32_t)(p & 15) << 20) | dv | (uint32_t)ss;
            p = iv[j].y; ss = sv[j].y & 1; b = (uint32_t)p >> 4;
            sl = atomicAdd(&curL[b], 1u);
            staging[sl] = ((uint32_t)(p & 15) << 20) | dv | (uint32_t)ss;
            p = iv[j].z; ss = sv[j].z & 1; b = (uint32_t)p >> 4;
            sl = atomicAdd(&curL[b], 1u);
            staging[sl] = ((uint32_t)(p & 15) << 20) | dv | (uint32_t)ss;
            p = iv[j].w; ss = sv[j].w & 1; b = (uint32_t)p >> 4;
            sl = atomicAdd(&curL[b], 1u);
            staging[sl] = ((uint32_t)(p & 15) << 20) | dv | (uint32_t)ss;
        }
        __syncthreads();
        // global dense base per half-bucket (device-scope atomic)
        if (t < NHB) gb[t] = atomicAdd(&gBase[t], cntL[t]);
        __syncthreads();
        // append groups densely: wave w copies its 32 half-buckets
        const int w = t >> 6;
        for (int i = 0; i < NHB / 16; ++i) {
            const int b = w * (NHB / 16) + i;
            const uint32_t c   = cntL[b];
            const uint32_t src = offL[b];
            const uint32_t g0  = gb[b];
            const uint32_t lim = (g0 < (uint32_t)CAPH) ? ((uint32_t)CAPH - g0) : 0u;
            const uint32_t cw  = c < lim ? c : lim;
            uint32_t* dst = dense + (size_t)b * CAPH + g0;
            for (uint32_t j2 = lane; j2 < cw; j2 += 64) dst[j2] = staging[src + j2];
        }
    } else {
        // ---------------- transpose (256 d per block, 4 tiles of 64) ----
        float* tile = reinterpret_cast<float*>(sh);   // [64][65], 4160 f32
        const int blk   = blockIdx.x - NBLKA;         // 0..2047
        const int dbase = blk * 256;
        const int c  = t & 15;                        // float4 column
        const int r  = t >> 4;                        // batch row 0..63
        const int a  = t & 15;                        // uint2 column (of 16)
        const int dr = t >> 4;                        // d row 0..63
#pragma unroll
        for (int it = 0; it < 4; ++it) {
            const int d0 = dbase + it * 64;
            float4 v = *reinterpret_cast<const float4*>(
                &x[(size_t)r * DIM + d0 + 4 * c]);
            __syncthreads();                  // prev pack done (no-op it=0)
            tile[r * 65 + 4 * c + 0] = v.x;
            tile[r * 65 + 4 * c + 1] = v.y;
            tile[r * 65 + 4 * c + 2] = v.z;
            tile[r * 65 + 4 * c + 3] = v.w;
            __syncthreads();
            uint32_t lo, hi;
            lo = f2bf(tile[(4 * a + 0) * 65 + dr] * 0.5f);
            hi = f2bf(tile[(4 * a + 1) * 65 + dr] * 0.5f);
            const uint32_t w0 = lo | (hi << 16);
            lo = f2bf(tile[(4 * a + 2) * 65 + dr] * 0.5f);
            hi = f2bf(tile[(4 * a + 3) * 65 + dr] * 0.5f);
            const uint32_t w1 = lo | (hi << 16);
            uint2 wv; wv.x = w0; wv.y = w1;
            *reinterpret_cast<uint2*>(&xT[(size_t)(d0 + dr) * 32 + 2 * a]) = wv;
        }
    }
}

// ==================== pass 2: direct-stream gather, no fine-bin =========
// 512 blocks x 1024 threads; block = half-bucket (16 p), 2 blocks/CU.
// Wave w streams segment [s0,s1) of the unsorted hb stream. Per entry:
// all lanes load the 128B xT row (k = lane&31; upper half duplicates the
// same line, benign), then a wave-uniform scalar switch on pv routes the
// two FMAs into 1 of 16 named register acc pairs. Zero LDS in hot loop.
// End: 4-round tree-reduce across 16 waves in LDS; full-line out writes.
#define G9_CASE(Q) case Q: acc0[Q] += v0; acc1[Q] += v1; break;
#define G9_SWITCH(PV)                                                     \
    switch (PV) {                                                         \
        G9_CASE(0)  G9_CASE(1)  G9_CASE(2)  G9_CASE(3)                    \
        G9_CASE(4)  G9_CASE(5)  G9_CASE(6)  G9_CASE(7)                    \
        G9_CASE(8)  G9_CASE(9)  G9_CASE(10) G9_CASE(11)                   \
        G9_CASE(12) G9_CASE(13) G9_CASE(14) G9_CASE(15)                   \
        default: break;                                                   \
    }

__global__ __launch_bounds__(1024) void gather9_kernel(
    const uint32_t* __restrict__ dense, const uint32_t* __restrict__ gBase,
    const uint32_t* __restrict__ xT, float* __restrict__ out)
{
    __shared__ float2 red2[8 * 528];         // 8 surfaces x 16q x 33 = 33,792 B
    const int t    = threadIdx.x;
    const int w    = t >> 6;                 // 0..15
    const int lane = t & 63;
    const int k    = lane & 31;              // u32 index in xT row (2 b's)
    const int hb   = blockIdx.x;             // half-bucket 0..511

    uint32_t nt = gBase[hb];
    if (nt > (uint32_t)CAPH) nt = (uint32_t)CAPH;
    const uint32_t* seg = dense + (size_t)hb * CAPH;
    const uint32_t s0 = (nt * (uint32_t)w) >> 4;
    const uint32_t s1 = (nt * (uint32_t)(w + 1)) >> 4;

    float acc0[16], acc1[16];
#pragma unroll
    for (int q = 0; q < 16; ++q) { acc0[q] = 0.f; acc1[q] = 0.f; }

    uint32_t base = s0;
    for (; base + 8 <= s1; base += 8) {
        uint32_t e8[8];
#pragma unroll
        for (int j = 0; j < 8; ++j) e8[j] = seg[base + j];     // uniform
        uint32_t u8[8];
#pragma unroll
        for (int j = 0; j < 8; ++j)                            // 8 in flight
            u8[j] = xT[(size_t)((e8[j] >> 1) & 0x7FFFFu) * 32 + k];
#pragma unroll
        for (int j = 0; j < 8; ++j) {
            const uint32_t u = u8[j] ^ ((e8[j] & 1u) ? 0u : 0x80008000u);
            const float v0 = __uint_as_float(u << 16);         // b = 2k
            const float v1 = __uint_as_float(u & 0xffff0000u); // b = 2k+1
            const int pv = __builtin_amdgcn_readfirstlane((int)((e8[j] >> 20) & 15u));
            G9_SWITCH(pv)
        }
    }
    for (; base < s1; ++base) {              // tail (<8 entries)
        const uint32_t e = seg[base];
        uint32_t u = xT[(size_t)((e >> 1) & 0x7FFFFu) * 32 + k];
        u ^= (e & 1u) ? 0u : 0x80008000u;
        const float v0 = __uint_as_float(u << 16);
        const float v1 = __uint_as_float(u & 0xffff0000u);
        const int pv = __builtin_amdgcn_readfirstlane((int)((e >> 20) & 15u));
        G9_SWITCH(pv)
    }

    // ---- tree reduce across 16 waves (lanes 0..31 carry the data) ----
#pragma unroll
    for (int stride = 8; stride >= 1; stride >>= 1) {
        if (w >= stride && w < 2 * stride && lane < 32) {
            float2* dst = red2 + (w - stride) * 528;
#pragma unroll
            for (int q = 0; q < 16; ++q)
                dst[q * 33 + k] = make_float2(acc0[q], acc1[q]);
        }
        __syncthreads();
        if (w < stride && lane < 32) {
            const float2* src = red2 + w * 528;
#pragma unroll
            for (int q = 0; q < 16; ++q) {
                float2 v = src[q * 33 + k];
                acc0[q] += v.x; acc1[q] += v.y;
            }
        }
        __syncthreads();
    }
    if (w == 0 && lane < 32) {
#pragma unroll
        for (int q = 0; q < 16; ++q)
            red2[q * 33 + k] = make_float2(acc0[q], acc1[q]);
    }
    __syncthreads();
    // out: thread t -> (b = t>>4, q = t&15); 16 consecutive q = 64B line
    {
        const int b = t >> 4, q = t & 15;
        const float2 vq = red2[q * 33 + (b >> 1)];
        out[(size_t)b * PROJ + hb * HBP + q] = (b & 1) ? vq.y : vq.x;
    }
}

// ------------------------------------------------- fallback (R3 scatter)
__device__ __forceinline__ void lds_fadd(uint32_t byte_addr, float v) {
    asm volatile("ds_add_f32 %0, %1" :: "v"(byte_addr), "v"(v) : "memory");
}
__device__ __forceinline__ void lds_fadd_off32k(uint32_t byte_addr, float v) {
    asm volatile("ds_add_f32 %0, %1 offset:32768" :: "v"(byte_addr), "v"(v) : "memory");
}

__global__ __launch_bounds__(1024) void sjlt_scatter(
    const float* __restrict__ x, const int4* __restrict__ idx4,
    const int4* __restrict__ sgn4, float* __restrict__ out)
{
    __shared__ float acc[4 * PROJ];
    for (int i = threadIdx.x; i < 4 * PROJ; i += 1024) acc[i] = 0.0f;
    __syncthreads();
    const int row0 = blockIdx.y * 4;
    const int dbeg = blockIdx.x * (DIM / 16);
    const uint32_t accBase = (uint32_t)(uintptr_t)(&acc[0]);
    const float* xr0 = x + (size_t)(row0 + 0) * DIM;
    const float* xr1 = x + (size_t)(row0 + 1) * DIM;
    const float* xr2 = x + (size_t)(row0 + 2) * DIM;
    const float* xr3 = x + (size_t)(row0 + 3) * DIM;
    for (int d = dbeg + (int)threadIdx.x; d < dbeg + DIM / 16; d += 1024) {
        const int4 iv = idx4[d];
        const int4 sv = sgn4[d];
        const uint32_t u0 = __float_as_uint(xr0[d]);
        const uint32_t u1 = __float_as_uint(xr1[d]);
        const uint32_t u2 = __float_as_uint(xr2[d]);
        const uint32_t u3 = __float_as_uint(xr3[d]);
        const int p[4] = {iv.x, iv.y, iv.z, iv.w};
        const int s[4] = {sv.x, sv.y, sv.z, sv.w};
#pragma unroll
        for (int j = 0; j < 4; ++j) {
            const uint32_t flip = (uint32_t)(s[j] ^ 1) << 31;
            const uint32_t a01  = accBase + ((uint32_t)p[j] << 2);
            const uint32_t a23  = a01 + 2u * 32768u;
            lds_fadd        (a01, __uint_as_float(u0 ^ flip));
            lds_fadd_off32k (a01, __uint_as_float(u1 ^ flip));
            lds_fadd        (a23, __uint_as_float(u2 ^ flip));
            lds_fadd_off32k (a23, __uint_as_float(u3 ^ flip));
        }
    }
    __syncthreads();
    for (int i = threadIdx.x; i < 4 * PROJ; i += 1024) {
        const int r  = i >> 13;
        const int pp = i & (PROJ - 1);
        unsafeAtomicAdd(&out[(size_t)(row0 + r) * PROJ + pp], acc[i] * 0.5f);
    }
}

// --------------------------------------------------------------- launch
extern "C" void kernel_launch(void* const* d_in, const int* in_sizes, int n_in,
                              void* d_out, int out_size, void* d_ws, size_t ws_size,
                              hipStream_t stream) {
    const float* x   = (const float*)d_in[0];
    const int4*  idx = (const int4*) d_in[1];
    const int4*  sgn = (const int4*) d_in[2];
    float*       out = (float*)d_out;

    // R14 layout: gBase[512] | dense[512*4608] | xT[DIM*32] = 76,548,096 B
    const size_t need = ((size_t)NHB + (size_t)NHB * CAPH + (size_t)DIM * 32) * 4;

    if (ws_size >= need) {
        uint32_t* gBase = (uint32_t*)d_ws;
        uint32_t* dense = gBase + NHB;
        uint32_t* xT    = dense + (size_t)NHB * CAPH;

        hipMemsetAsync(gBase, 0, NHB * sizeof(uint32_t), stream);  // 2 KB
        prep_kernel   <<<NBLKA + TBLK, 1024, 0, stream>>>(
            x, idx, sgn, gBase, dense, xT);
        gather9_kernel<<<NHB,          1024, 0, stream>>>(dense, gBase, xT, out);
    } else {
        // ws too small: R3 LDS-scatter path (passes at ~830 us)
        hipMemsetAsync(d_out, 0, (size_t)out_size * sizeof(float), stream);
        dim3 grid(16, 16);
        sjlt_scatter<<<grid, 1024, 0, stream>>>(x, idx, sgn, out);
    }
}